// Round 16
// baseline (503.480 us; speedup 1.0000x reference)
//
#include <hip/hip_runtime.h>
#include <hip/hip_bf16.h>
#include <math.h>

#define BB 4
#define SEQ 8192
#define DIM 512
#define GG 32
#define NPG 256
#define QKD 128
#define HIDD 512

typedef unsigned short u16;
typedef unsigned int u32;

using s16x8 = __attribute__((ext_vector_type(8))) short;
using f32x4 = __attribute__((ext_vector_type(4))) float;

__device__ __forceinline__ float bf2f(u16 u) { return __uint_as_float(((u32)u) << 16); }
__device__ __forceinline__ u16 f2bf(float f) {
  u32 b = __float_as_uint(f);
  return (u16)((b + 0x7FFFu + ((b >> 16) & 1u)) >> 16);
}
__device__ __forceinline__ float silu_f(float x) { return x / (1.f + expf(-x)); }
__device__ __forceinline__ float silu_fast(float x) { return x / (1.f + __expf(-x)); }
__device__ __forceinline__ float4 fma4(float4 a, float4 b, float4 c) {
  return make_float4(a.x*b.x+c.x, a.y*b.y+c.y, a.z*b.z+c.z, a.w*b.w+c.w);
}
__device__ __forceinline__ float4 mul4(float4 a, float4 b) {
  return make_float4(a.x*b.x, a.y*b.y, a.z*b.z, a.w*b.w);
}
#define LD4(p, off) (*(const float4*)((p) + (off)))

// async global->LDS, 16B per lane; LDS dest = wave-uniform base + lane*16
__device__ __forceinline__ void gl_lds16(const u16* g, u16* l) {
  __builtin_amdgcn_global_load_lds((const __attribute__((address_space(1))) void*)g,
                                   (__attribute__((address_space(3))) void*)l, 16, 0, 0);
}

// elementwise scale 8 bf16 by f32 params: out = v*s
__device__ __forceinline__ s16x8 mul8(s16x8 v, float4 s0, float4 s1) {
  union U { s16x8 x; u16 u[8]; };
  U in; in.x = v; U r;
  r.u[0] = f2bf(bf2f(in.u[0]) * s0.x);
  r.u[1] = f2bf(bf2f(in.u[1]) * s0.y);
  r.u[2] = f2bf(bf2f(in.u[2]) * s0.z);
  r.u[3] = f2bf(bf2f(in.u[3]) * s0.w);
  r.u[4] = f2bf(bf2f(in.u[4]) * s1.x);
  r.u[5] = f2bf(bf2f(in.u[5]) * s1.y);
  r.u[6] = f2bf(bf2f(in.u[6]) * s1.z);
  r.u[7] = f2bf(bf2f(in.u[7]) * s1.w);
  return r.x;
}

// ---------------- Kernel 1: LayerNorm + global seq-shift scatter (f32 + bf16 copies) ----------------
__global__ __launch_bounds__(256) void k_ln(const float* __restrict__ x,
    const float* __restrict__ lg, const float* __restrict__ lb,
    float* __restrict__ xs, u16* __restrict__ xsb) {
  const int row = blockIdx.x;               // b*SEQ + s
  const int s = row & (SEQ - 1);
  const int t = threadIdx.x;
  const float* xr = x + (size_t)row * DIM;
  float v0 = xr[t], v1 = xr[t + 256];
  float sum = v0 + v1, sq = v0 * v0 + v1 * v1;
  #pragma unroll
  for (int o = 32; o; o >>= 1) { sum += __shfl_down(sum, o); sq += __shfl_down(sq, o); }
  __shared__ float sm[8];
  const int w = t >> 6;
  if ((t & 63) == 0) { sm[w] = sum; sm[4 + w] = sq; }
  __syncthreads();
  if (t == 0) {
    float S = sm[0] + sm[1] + sm[2] + sm[3];
    float Q = sm[4] + sm[5] + sm[6] + sm[7];
    float mu = S * (1.f / DIM);
    float var = Q * (1.f / DIM) - mu * mu;
    sm[0] = mu; sm[4] = rsqrtf(var + 1e-5f);
  }
  __syncthreads();
  const float mu = sm[0], rs = sm[4];
  float y0 = (v0 - mu) * rs * lg[t] + lb[t];
  float y1 = (v1 - mu) * rs * lg[t + 256] + lb[t + 256];
  xs[(size_t)row * DIM + t + 256] = y1;
  xsb[(size_t)row * DIM + t + 256] = f2bf(y1);
  if (s + 1 < SEQ) {
    xs[(size_t)(row + 1) * DIM + t] = y0;
    xsb[(size_t)(row + 1) * DIM + t] = f2bf(y0);
  }
  if (s == 0) { xs[(size_t)row * DIM + t] = 0.f; xsb[(size_t)row * DIM + t] = 0; }
}

// ---------------- weight transpose f32 [K][N] -> bf16 [rowOff+n][dstLD] ----------------
__global__ __launch_bounds__(256) void k_trw(const float* __restrict__ src, u16* __restrict__ dst,
    int N, int dstLD, int rowOff) {
  __shared__ u16 T[64][66];
  const int t = threadIdx.x;
  const int k0 = blockIdx.x * 64, n0 = blockIdx.y * 64;
  #pragma unroll
  for (int i = 0; i < 16; ++i) {
    int idx = t + 256 * i;
    int r = idx >> 6, c = idx & 63;
    T[c][r] = f2bf(src[(size_t)(k0 + r) * N + n0 + c]);
  }
  __syncthreads();
  #pragma unroll
  for (int i = 0; i < 16; ++i) {
    int idx = t + 256 * i;
    int r = idx >> 6, c = idx & 63;
    dst[(size_t)(rowOff + n0 + r) * dstLD + k0 + c] = T[r][c];
  }
}

// ---------------- HIDT [bg][e=512][j=256] -> HIDR [bg*256+j][512] (bf16) ----------------
__global__ __launch_bounds__(256) void k_trh(const u16* __restrict__ hidt, u16* __restrict__ hidr) {
  __shared__ u16 T[64][66];
  const int t = threadIdx.x;
  const int j0 = blockIdx.x * 64;
  const int e0 = blockIdx.y * 64;
  const int bg = blockIdx.z;
  #pragma unroll
  for (int i = 0; i < 16; ++i) {
    int idx = t + 256 * i; int r = idx >> 6, c = idx & 63;
    T[c][r] = hidt[((size_t)bg * 512 + e0 + r) * 256 + j0 + c];
  }
  __syncthreads();
  #pragma unroll
  for (int i = 0; i < 16; ++i) {
    int idx = t + 256 * i; int r = idx >> 6, c = idx & 63;
    hidr[((size_t)bg * 256 + j0 + r) * 512 + e0 + c] = T[r][c];
  }
}

// ---------------- Kernel 2: m97-style MFMA GEMM xsb @ [w_qk | w_hidden | w_gate] ----------------
__global__ __launch_bounds__(256, 3) void k_gemm1m(const u16* __restrict__ xsb,
    const u16* __restrict__ w1t, u16* __restrict__ qk, u16* __restrict__ hidt,
    u16* __restrict__ gate, u16* __restrict__ xg) {
  __shared__ u16 As[128 * 64];
  __shared__ u16 Bs[128 * 64];
  const int t = threadIdx.x;
  const int blk = blockIdx.x;                 // 3328 = 8 XCD x 32 m x 13 n
  const int xcd = blk & 7;
  const int loc = blk >> 3;                   // 0..415
  const int m0 = (xcd * 32 + loc / 13) * 128;
  const int n0 = (loc % 13) * 128;
  const int w = t >> 6, l = t & 63, lr = l & 15, lq = l >> 4;
  const int wr = (w >> 1) * 64, wc = (w & 1) * 64;
  const int rI = l >> 3;                      // row within 8-row issue
  const int c8 = (l & 7) ^ rI;                // pre-swizzled source col8
  const int slotA = lq ^ (lr & 7);            // read slot, kk=0 half
  const int slotB = (4 + lq) ^ (lr & 7);      // read slot, kk=32 half
  f32x4 acc[4][4];
  #pragma unroll
  for (int i = 0; i < 4; ++i)
    #pragma unroll
    for (int j = 0; j < 4; ++j) acc[i][j] = (f32x4){0.f, 0.f, 0.f, 0.f};
  for (int tt = 0; tt < 8; ++tt) {
    const int k0 = tt * 64;
    #pragma unroll
    for (int i = 0; i < 4; ++i) {
      const int br = w * 32 + i * 8;
      gl_lds16(xsb + (size_t)(m0 + br + rI) * 512 + k0 + c8 * 8, &As[br * 64]);
      gl_lds16(w1t + (size_t)(n0 + br + rI) * 512 + k0 + c8 * 8, &Bs[br * 64]);
    }
    __syncthreads();
    #pragma unroll
    for (int kk = 0; kk < 2; ++kk) {
      const int slot = kk ? slotB : slotA;
      s16x8 af[4], bf[4];
      #pragma unroll
      for (int fi = 0; fi < 4; ++fi) af[fi] = *(const s16x8*)&As[(wr + fi * 16 + lr) * 64 + slot * 8];
      #pragma unroll
      for (int fj = 0; fj < 4; ++fj) bf[fj] = *(const s16x8*)&Bs[(wc + fj * 16 + lr) * 64 + slot * 8];
      #pragma unroll
      for (int fi = 0; fi < 4; ++fi)
        #pragma unroll
        for (int fj = 0; fj < 4; ++fj)
          acc[fi][fj] = __builtin_amdgcn_mfma_f32_16x16x32_bf16(af[fi], bf[fj], acc[fi][fj], 0, 0, 0);
    }
    __syncthreads();
  }
  if (n0 == 0) {
    #pragma unroll
    for (int fi = 0; fi < 4; ++fi)
      #pragma unroll
      for (int fj = 0; fj < 4; ++fj) {
        const int n = wc + fj * 16 + lr;
        const int mb = m0 + wr + fi * 16 + lq * 4;
        #pragma unroll
        for (int r = 0; r < 4; ++r)
          qk[(size_t)(mb + r) * QKD + n] = f2bf(acc[fi][fj][r]);
      }
  } else if (n0 < 640) {
    const int bg = m0 >> 8;
    #pragma unroll
    for (int fi = 0; fi < 4; ++fi)
      #pragma unroll
      for (int fj = 0; fj < 4; ++fj) {
        const int e = n0 - 128 + wc + fj * 16 + lr;
        const int j0 = (m0 & 255) + wr + fi * 16 + lq * 4;
        ushort4 pk;
        pk.x = f2bf(acc[fi][fj][0]); pk.y = f2bf(acc[fi][fj][1]);
        pk.z = f2bf(acc[fi][fj][2]); pk.w = f2bf(acc[fi][fj][3]);
        *(ushort4*)(hidt + ((size_t)bg * 512 + e) * 256 + j0) = pk;
      }
  } else if (n0 < 1152) {
    #pragma unroll
    for (int fi = 0; fi < 4; ++fi)
      #pragma unroll
      for (int fj = 0; fj < 4; ++fj) {
        const int n = n0 - 640 + wc + fj * 16 + lr;
        const int mb = m0 + wr + fi * 16 + lq * 4;
        #pragma unroll
        for (int r = 0; r < 4; ++r)
          gate[(size_t)(mb + r) * HIDD + n] = f2bf(acc[fi][fj][r]);
      }
  } else {
    #pragma unroll
    for (int fi = 0; fi < 4; ++fi)
      #pragma unroll
      for (int fj = 0; fj < 4; ++fj) {
        const int n = n0 - 1152 + wc + fj * 16 + lr;
        const int mb = m0 + wr + fi * 16 + lq * 4;
        #pragma unroll
        for (int r = 0; r < 4; ++r)
          xg[(size_t)(mb + r) * HIDD + n] = f2bf(silu_f(acc[fi][fj][r]));
      }
  }
}

// ---------------- Kernel 3: fused qk_mean + per-j bias b[bg][h][j] ----------------
// Phase 1: column means of this bg's qk tile (into LDS + qm).
// Phase 2: b_j = dot(qk_src(j), Oq*Sk) per head (softmax-invariant decomposition).
__global__ __launch_bounds__(256) void k_qkmb(const u16* __restrict__ qk,
    const float* __restrict__ g4, const float* __restrict__ b4,
    const float* __restrict__ g2, const float* __restrict__ b2,
    float* __restrict__ qm, float* __restrict__ bjs) {
  __shared__ float smQ[128];
  __shared__ float tmp[256];
  const int bg = blockIdx.x;
  const size_t grpRow = (size_t)bg * NPG;
  const int t = threadIdx.x;
  {
    const int c = t & 127, half = t >> 7;
    const u16* p = qk + (grpRow + half * 128) * QKD + c;
    float s = 0.f;
    for (int i = 0; i < 128; ++i) s += bf2f(p[(size_t)i * QKD]);
    tmp[t] = s;
  }
  __syncthreads();
  if (t < 128) {
    float m = (tmp[t] + tmp[t + 128]) * (1.f / NPG);
    smQ[t] = m;
    qm[bg * QKD + t] = m;
  }
  __syncthreads();
  const int h = t >> 6, l = t & 63;
  const bool sh = (h >= 2);
  const int cbase = (h & 1) << 6;
  const int dd = (l & 7) * 8;                 // this lane's 8-col slice
  float c[8];
  #pragma unroll
  for (int e = 0; e < 8; ++e) {
    int d = cbase + dd + e;
    float qmv = smQ[d];
    float qsc = qmv * g4[2 * QKD + d] + b4[2 * QKD + d];
    float qof = qmv * g4[d] + b4[d];
    float ksc = qmv * g4[3 * QKD + d] + b4[3 * QKD + d];
    float Oq, Sk;
    if (!sh) { Oq = qof; Sk = ksc; }
    else {
      float qso = qmv * g2[d] + b2[d];
      Oq = qof * qsc + qso;
      Sk = ksc * ksc;
    }
    c[e] = Oq * Sk;
  }
  float* bp = bjs + ((size_t)bg * 4 + h) * NPG;
  for (int jb = 0; jb < NPG; jb += 8) {
    int j = jb + (l >> 3);
    int src = sh ? (j ? j - 1 : 0) : j;
    const u16* row = qk + (grpRow + src) * QKD + cbase + dd;
    float s = 0.f;
    #pragma unroll
    for (int e = 0; e < 8; ++e) s += bf2f(row[e]) * c[e];
    s += __shfl_xor(s, 1); s += __shfl_xor(s, 2); s += __shfl_xor(s, 4);
    if ((l & 7) == 0) bp[j] = s;
  }
}

// ---------------- Kernel 4: decomposed attention + T14 V-octant register prefetch ----------------
__global__ __launch_bounds__(256, 4) void k_attn(const u16* __restrict__ qk,
    const float* __restrict__ qm, const float* __restrict__ g4, const float* __restrict__ b4,
    const float* __restrict__ bjs, const u16* __restrict__ hidt,
    const u16* __restrict__ gate, u16* __restrict__ out4) {
  __shared__ u16 Vs[64][264];                 // one 64-e x (causal j) octant of V^T
  const int t = threadIdx.x;
  const int l = t & 63;
  const int h = t >> 6;                       // wave = head
  const bool sh = (h >= 2);
  const int blk = blockIdx.x;
  const int xcd = blk & 7;
  const int bb = blk >> 3;                    // 0..255 per XCD
  const int bg = xcd * 16 + (bb >> 4);        // 16 bgs per XCD
  const int iw = 15 - (bb & 15);              // heavy tiles first within each bg
  const size_t grpRow = (size_t)bg * NPG;
  const int cbase = (h & 1) << 6;
  const int lr = l & 15, lq = l >> 4;
  const int cA = cbase + 8 * lq;
  const int ntmax = iw, jtmax = iw >> 1;
  const int irow = iw * 16 + lr;
  // ---- W = Sq*Sk for this lane's 16 cols ----
  const float* qmp = qm + bg * QKD;
  float4 qmA = LD4(qmp, cA),      qmB = LD4(qmp, cA + 4);
  float4 qmC = LD4(qmp, cA + 32), qmD = LD4(qmp, cA + 36);
  float4 wA = mul4(fma4(qmA, LD4(g4, 2*QKD+cA),    LD4(b4, 2*QKD+cA)),
                   fma4(qmA, LD4(g4, 3*QKD+cA),    LD4(b4, 3*QKD+cA)));
  float4 wB = mul4(fma4(qmB, LD4(g4, 2*QKD+cA+4),  LD4(b4, 2*QKD+cA+4)),
                   fma4(qmB, LD4(g4, 3*QKD+cA+4),  LD4(b4, 3*QKD+cA+4)));
  float4 wC = mul4(fma4(qmC, LD4(g4, 2*QKD+cA+32), LD4(b4, 2*QKD+cA+32)),
                   fma4(qmC, LD4(g4, 3*QKD+cA+32), LD4(b4, 3*QKD+cA+32)));
  float4 wD = mul4(fma4(qmD, LD4(g4, 2*QKD+cA+36), LD4(b4, 2*QKD+cA+36)),
                   fma4(qmD, LD4(g4, 3*QKD+cA+36), LD4(b4, 3*QKD+cA+36)));
  if (sh) { wA = mul4(wA, wA); wB = mul4(wB, wB); wC = mul4(wC, wC); wD = mul4(wD, wD); }
  const float scl = 0.17677669529663687f;     // 1/sqrt(32)
  // ---- Q fragment (B-operand: col = lr = q-row i): raw qk row * W ----
  const int qsrc = sh ? (irow ? irow - 1 : 0) : irow;
  const u16* qrow = qk + (grpRow + qsrc) * QKD + cA;
  s16x8 qb0 = mul8(*(const s16x8*)qrow,        wA, wB);
  s16x8 qb1 = mul8(*(const s16x8*)(qrow + 32), wC, wD);
  // ---- QK^T (A = RAW qk row-tile, causally bounded) ----
  f32x4 sfr[16];
  #pragma unroll
  for (int nt = 0; nt < 16; ++nt) if (nt <= ntmax) {
    const int jr = nt * 16 + lr;
    const int ksrc = sh ? (jr ? jr - 1 : 0) : jr;
    const u16* kr = qk + (grpRow + ksrc) * QKD + cA;
    s16x8 ka0 = *(const s16x8*)kr;
    s16x8 ka1 = *(const s16x8*)(kr + 32);
    f32x4 c = {0.f, 0.f, 0.f, 0.f};
    c = __builtin_amdgcn_mfma_f32_16x16x32_bf16(ka0, qb0, c, 0, 0, 0);
    c = __builtin_amdgcn_mfma_f32_16x16x32_bf16(ka1, qb1, c, 0, 0, 0);
    sfr[nt] = c;
  }
  // ---- add per-j bias ----
  const float* bp = bjs + ((size_t)bg * 4 + h) * NPG;
  #pragma unroll
  for (int nt = 0; nt < 16; ++nt) if (nt <= ntmax) {
    float4 bv = LD4(bp, nt * 16 + lq * 4);
    f32x4 c = sfr[nt];
    c[0] += bv.x; c[1] += bv.y; c[2] += bv.z; c[3] += bv.w;
    sfr[nt] = c;
  }
  // ---- softmax over j for this lane's row ----
  float mx = -3.4e38f;
  #pragma unroll
  for (int nt = 0; nt < 16; ++nt) if (nt <= ntmax) {
    #pragma unroll
    for (int r = 0; r < 4; ++r) {
      int j = nt * 16 + lq * 4 + r;
      if (j <= irow) mx = fmaxf(mx, sfr[nt][r] * scl);
    }
  }
  mx = fmaxf(mx, __shfl_xor(mx, 16));
  mx = fmaxf(mx, __shfl_xor(mx, 32));
  float sum = 0.f;
  u32 p01[16], p23[16];
  #pragma unroll
  for (int nt = 0; nt < 16; ++nt) { p01[nt] = 0u; p23[nt] = 0u; }
  #pragma unroll
  for (int nt = 0; nt < 16; ++nt) if (nt <= ntmax) {
    int j = nt * 16 + lq * 4;
    float e0 = (j + 0 <= irow) ? __expf(sfr[nt][0] * scl - mx) : 0.f;
    float e1 = (j + 1 <= irow) ? __expf(sfr[nt][1] * scl - mx) : 0.f;
    float e2 = (j + 2 <= irow) ? __expf(sfr[nt][2] * scl - mx) : 0.f;
    float e3 = (j + 3 <= irow) ? __expf(sfr[nt][3] * scl - mx) : 0.f;
    sum += (e0 + e1) + (e2 + e3);
    p01[nt] = (u32)f2bf(e0) | ((u32)f2bf(e1) << 16);
    p23[nt] = (u32)f2bf(e2) | ((u32)f2bf(e3) << 16);
  }
  sum += __shfl_xor(sum, 16);
  sum += __shfl_xor(sum, 32);
  const float inv = 1.f / sum;
  // ---- build P^T B-frags via in-wave shuffles ----
  const int srcA = (l & 15) | ((l & 16) << 1);   // lr + 32*(lq&1)
  const int srcB = srcA + 16;
  const bool hi = (l >= 32);
  s16x8 bfr[8];
  #pragma unroll
  for (int jt = 0; jt < 8; ++jt) if (jt <= jtmax) {
    u32 a0 = __shfl((int)p01[2 * jt], srcA), a1 = __shfl((int)p23[2 * jt], srcA);
    u32 a2 = __shfl((int)p01[2 * jt], srcB), a3 = __shfl((int)p23[2 * jt], srcB);
    u32 b0 = __shfl((int)p01[2 * jt + 1], srcA), b1 = __shfl((int)p23[2 * jt + 1], srcA);
    u32 b2 = __shfl((int)p01[2 * jt + 1], srcB), b3 = __shfl((int)p23[2 * jt + 1], srcB);
    union { u32 u[4]; s16x8 v; } bb2;
    bb2.u[0] = hi ? b0 : a0; bb2.u[1] = hi ? b1 : a1;
    bb2.u[2] = hi ? b2 : a2; bb2.u[3] = hi ? b3 : a3;
    bfr[jt] = bb2.v;
  }
  // ---- PV over 8 e-octants: T14 register prefetch, causally-bounded staging ----
  const u16* vtb = hidt + (size_t)bg * (512 * 256);
  const size_t srow = grpRow + irow;
  const u16* gp = gate + srow * HIDD;
  u16* op = out4 + srow * 2048 + ((size_t)h << 9);
  const int vrow = t >> 2, vcol8 = (t & 3) * 8;
  uint4 pv[8];
  #pragma unroll
  for (int jt2 = 0; jt2 < 8; ++jt2) if (jt2 <= jtmax)
    pv[jt2] = *(const uint4*)(vtb + (size_t)vrow * 256 + jt2 * 32 + vcol8);
  for (int oct = 0; oct < 8; ++oct) {
    __syncthreads();                          // previous octant fully consumed
    #pragma unroll
    for (int jt2 = 0; jt2 < 8; ++jt2) if (jt2 <= jtmax)
      *(uint4*)&Vs[vrow][jt2 * 32 + vcol8] = pv[jt2];
    if (oct < 7) {                            // issue next octant's loads (hide under MFMA)
      const u16* srcn = vtb + (size_t)(oct + 1) * 64 * 256;
      #pragma unroll
      for (int jt2 = 0; jt2 < 8; ++jt2) if (jt2 <= jtmax)
        pv[jt2] = *(const uint4*)(srcn + (size_t)vrow * 256 + jt2 * 32 + vcol8);
    }
    __syncthreads();
    f32x4 acc[4];
    #pragma unroll
    for (int ef = 0; ef < 4; ++ef) acc[ef] = (f32x4){0.f, 0.f, 0.f, 0.f};
    #pragma unroll
    for (int jt = 0; jt < 8; ++jt) if (jt <= jtmax) {
      __builtin_amdgcn_s_setprio(1);
      #pragma unroll
      for (int ef = 0; ef < 4; ++ef) {
        s16x8 va = *(const s16x8*)&Vs[ef * 16 + lr][jt * 32 + 8 * lq];
        acc[ef] = __builtin_amdgcn_mfma_f32_16x16x32_bf16(va, bfr[jt], acc[ef], 0, 0, 0);
      }
      __builtin_amdgcn_s_setprio(0);
    }
    #pragma unroll
    for (int ef = 0; ef < 4; ++ef) {
      const int e = oct * 64 + ef * 16 + lq * 4;
      ushort4 gu = *(const ushort4*)(gp + e);
      ushort4 ov;
      ov.x = f2bf(silu_fast(acc[ef][0] * inv) * bf2f(gu.x));
      ov.y = f2bf(silu_fast(acc[ef][1] * inv) * bf2f(gu.y));
      ov.z = f2bf(silu_fast(acc[ef][2] * inv) * bf2f(gu.z));
      ov.w = f2bf(silu_fast(acc[ef][3] * inv) * bf2f(gu.w));
      *(ushort4*)(op + e) = ov;
    }
  }
}

// ---------------- Kernel 5: m97-style MFMA GEMM residual(2560) @ w_out + epilogue ----------------
__global__ __launch_bounds__(256, 3) void k_gemm2m(const u16* __restrict__ hidr,
    const u16* __restrict__ out4, const u16* __restrict__ wt,
    const u16* __restrict__ xg, float* __restrict__ out) {
  __shared__ u16 As[128 * 64];
  __shared__ u16 Bs[128 * 64];
  const int t = threadIdx.x;
  const int blk = blockIdx.x;                 // 1024 = 8 XCD x 32 m x 4 n
  const int xcd = blk & 7;
  const int loc = blk >> 3;                   // 0..127
  const int m0 = (xcd * 32 + (loc >> 2)) * 128;
  const int n0 = (loc & 3) * 128;
  const int w = t >> 6, l = t & 63, lr = l & 15, lq = l >> 4;
  const int wr = (w >> 1) * 64, wc = (w & 1) * 64;
  const int rI = l >> 3;
  const int c8 = (l & 7) ^ rI;
  const int slotA = lq ^ (lr & 7);
  const int slotB = (4 + lq) ^ (lr & 7);
  f32x4 acc[4][4];
  #pragma unroll
  for (int i = 0; i < 4; ++i)
    #pragma unroll
    for (int j = 0; j < 4; ++j) acc[i][j] = (f32x4){0.f, 0.f, 0.f, 0.f};
  for (int tt = 0; tt < 40; ++tt) {
    const int k0 = tt * 64;
    const u16* ab; size_t ald; int ko;
    if (k0 < 512) { ab = hidr; ald = 512;  ko = k0; }
    else          { ab = out4; ald = 2048; ko = k0 - 512; }
    #pragma unroll
    for (int i = 0; i < 4; ++i) {
      const int br = w * 32 + i * 8;
      gl_lds16(ab + (size_t)(m0 + br + rI) * ald + ko + c8 * 8, &As[br * 64]);
      gl_lds16(wt + (size_t)(n0 + br + rI) * 2560 + k0 + c8 * 8, &Bs[br * 64]);
    }
    __syncthreads();
    #pragma unroll
    for (int kk = 0; kk < 2; ++kk) {
      const int slot = kk ? slotB : slotA;
      s16x8 af[4], bf[4];
      #pragma unroll
      for (int fi = 0; fi < 4; ++fi) af[fi] = *(const s16x8*)&As[(wr + fi * 16 + lr) * 64 + slot * 8];
      #pragma unroll
      for (int fj = 0; fj < 4; ++fj) bf[fj] = *(const s16x8*)&Bs[(wc + fj * 16 + lr) * 64 + slot * 8];
      #pragma unroll
      for (int fi = 0; fi < 4; ++fi)
        #pragma unroll
        for (int fj = 0; fj < 4; ++fj)
          acc[fi][fj] = __builtin_amdgcn_mfma_f32_16x16x32_bf16(af[fi], bf[fj], acc[fi][fj], 0, 0, 0);
    }
    __syncthreads();
  }
  #pragma unroll
  for (int fi = 0; fi < 4; ++fi)
    #pragma unroll
    for (int fj = 0; fj < 4; ++fj) {
      const int n = n0 + wc + fj * 16 + lr;
      const int mb = m0 + wr + fi * 16 + lq * 4;
      #pragma unroll
      for (int r = 0; r < 4; ++r) {
        const size_t idx = (size_t)(mb + r) * DIM + n;
        out[idx] = acc[fi][fj][r] * bf2f(xg[idx]) + out[idx];   // out holds xs (in-place)
      }
    }
}

extern "C" void kernel_launch(void* const* d_in, const int* in_sizes, int n_in,
                              void* d_out, int out_size, void* d_ws, size_t ws_size,
                              hipStream_t stream) {
  const float* x        = (const float*)d_in[0];
  const float* lg       = (const float*)d_in[1];
  const float* lb       = (const float*)d_in[2];
  const float* w_qk     = (const float*)d_in[3];
  const float* g4       = (const float*)d_in[4];
  const float* b4       = (const float*)d_in[5];
  const float* g2       = (const float*)d_in[6];
  const float* b2       = (const float*)d_in[7];
  const float* w_hidden = (const float*)d_in[8];
  const float* w_gate   = (const float*)d_in[9];
  const float* w_out    = (const float*)d_in[10];
  // ws layout (bytes), total 248,184,832 (<= R2-proven 251,723,776):
  //   QM   f32  @ 0              65,536
  //   HIDT bf16 @ 65,536     33,554,432   [bg][e][j]
  //   GATE bf16 @ 33,619,968 33,554,432   (HIDR overlays after attn)
  //   XG   bf16 @ 67,174,400 33,554,432
  //   QK   bf16 @ 100,728,832 8,388,608
  //   W1T  bf16 @ 109,117,440 1,703,936   [1664][512]
  //   WT   bf16 @ 110,821,376 2,621,440   [512][2560]
  //   OUT4 bf16 @ 113,442,816 134,217,728
  //   BJS  f32  @ 247,660,544    524,288  [bg][h][256] softmax bias
  // Overlays: HIDR (33,554,432) @ GATE  — written by k_trh AFTER attn (GATE dead).
  //           XSB  (33,554,432) @ OUT4  — written by k_ln, read by gemm1m; OUT4 is
  //                                       written by attn strictly AFTER gemm1m reads.
  // xs (f32) lives in d_out, overwritten in-place by k_gemm2m epilogue.
  if (ws_size < 248184832ull) return;
  char* ws = (char*)d_ws;
  float* QM   = (float*)(ws + 0);
  u16*   HIDT = (u16*)  (ws + 65536);
  u16*   GATE = (u16*)  (ws + 33619968);
  u16*   XG   = (u16*)  (ws + 67174400);
  u16*   QKb  = (u16*)  (ws + 100728832);
  u16*   W1T  = (u16*)  (ws + 109117440);
  u16*   WT   = (u16*)  (ws + 110821376);
  u16*   OUT4 = (u16*)  (ws + 113442816);
  u16*   XSB  = (u16*)  (ws + 113442816);   // overlay on OUT4 (pre-attn lifetime)
  u16*   HIDR = (u16*)  (ws + 33619968);    // overlay on GATE (post-attn)
  float* BJS  = (float*)(ws + 247660544);
  float* XS   = (float*)d_out;
  float* OUT  = (float*)d_out;

  k_ln<<<BB * SEQ, 256, 0, stream>>>(x, lg, lb, XS, XSB);
  k_trw<<<dim3(8, 2),  256, 0, stream>>>(w_qk,     W1T, 128,  512,  0);
  k_trw<<<dim3(8, 16), 256, 0, stream>>>(w_hidden, W1T, 1024, 512,  128);
  k_trw<<<dim3(8, 8),  256, 0, stream>>>(w_gate,   W1T, 512,  512,  1152);
  k_trw<<<dim3(40, 8), 256, 0, stream>>>(w_out,    WT,  512,  2560, 0);
  k_gemm1m<<<3328, 256, 0, stream>>>(XSB, W1T, QKb, HIDT, GATE, XG);
  k_qkmb<<<BB * GG, 256, 0, stream>>>(QKb, g4, b4, g2, b2, QM, BJS);
  k_attn<<<BB * GG * 16, 256, 0, stream>>>(QKb, QM, g4, b4, BJS, HIDT, GATE, OUT4);
  k_trh<<<dim3(4, 8, 128), 256, 0, stream>>>(HIDT, HIDR);
  k_gemm2m<<<1024, 256, 0, stream>>>(HIDR, OUT4, WT, XG, OUT);
}

// Round 17
// 418.561 us; speedup vs baseline: 1.2029x; 1.2029x over previous
//
#include <hip/hip_runtime.h>
#include <hip/hip_bf16.h>
#include <math.h>

#define BB 4
#define SEQ 8192
#define DIM 512
#define GG 32
#define NPG 256
#define QKD 128
#define HIDD 512

typedef unsigned short u16;
typedef unsigned int u32;

using s16x8 = __attribute__((ext_vector_type(8))) short;
using f32x4 = __attribute__((ext_vector_type(4))) float;

__device__ __forceinline__ float bf2f(u16 u) { return __uint_as_float(((u32)u) << 16); }
__device__ __forceinline__ u16 f2bf(float f) {
  u32 b = __float_as_uint(f);
  return (u16)((b + 0x7FFFu + ((b >> 16) & 1u)) >> 16);
}
__device__ __forceinline__ float silu_f(float x) { return x / (1.f + expf(-x)); }
__device__ __forceinline__ float silu_fast(float x) { return x / (1.f + __expf(-x)); }
__device__ __forceinline__ float4 fma4(float4 a, float4 b, float4 c) {
  return make_float4(a.x*b.x+c.x, a.y*b.y+c.y, a.z*b.z+c.z, a.w*b.w+c.w);
}
__device__ __forceinline__ float4 mul4(float4 a, float4 b) {
  return make_float4(a.x*b.x, a.y*b.y, a.z*b.z, a.w*b.w);
}
#define LD4(p, off) (*(const float4*)((p) + (off)))

// async global->LDS, 16B per lane; LDS dest = wave-uniform base + lane*16
__device__ __forceinline__ void gl_lds16(const u16* g, u16* l) {
  __builtin_amdgcn_global_load_lds((const __attribute__((address_space(1))) void*)g,
                                   (__attribute__((address_space(3))) void*)l, 16, 0, 0);
}

// elementwise scale 8 bf16 by f32 params: out = v*s
__device__ __forceinline__ s16x8 mul8(s16x8 v, float4 s0, float4 s1) {
  union U { s16x8 x; u16 u[8]; };
  U in; in.x = v; U r;
  r.u[0] = f2bf(bf2f(in.u[0]) * s0.x);
  r.u[1] = f2bf(bf2f(in.u[1]) * s0.y);
  r.u[2] = f2bf(bf2f(in.u[2]) * s0.z);
  r.u[3] = f2bf(bf2f(in.u[3]) * s0.w);
  r.u[4] = f2bf(bf2f(in.u[4]) * s1.x);
  r.u[5] = f2bf(bf2f(in.u[5]) * s1.y);
  r.u[6] = f2bf(bf2f(in.u[6]) * s1.z);
  r.u[7] = f2bf(bf2f(in.u[7]) * s1.w);
  return r.x;
}

// ---------------- Kernel 1: LayerNorm + global seq-shift scatter (f32 + bf16 copies) ----------------
__global__ __launch_bounds__(256) void k_ln(const float* __restrict__ x,
    const float* __restrict__ lg, const float* __restrict__ lb,
    float* __restrict__ xs, u16* __restrict__ xsb) {
  const int row = blockIdx.x;               // b*SEQ + s
  const int s = row & (SEQ - 1);
  const int t = threadIdx.x;
  const float* xr = x + (size_t)row * DIM;
  float v0 = xr[t], v1 = xr[t + 256];
  float sum = v0 + v1, sq = v0 * v0 + v1 * v1;
  #pragma unroll
  for (int o = 32; o; o >>= 1) { sum += __shfl_down(sum, o); sq += __shfl_down(sq, o); }
  __shared__ float sm[8];
  const int w = t >> 6;
  if ((t & 63) == 0) { sm[w] = sum; sm[4 + w] = sq; }
  __syncthreads();
  if (t == 0) {
    float S = sm[0] + sm[1] + sm[2] + sm[3];
    float Q = sm[4] + sm[5] + sm[6] + sm[7];
    float mu = S * (1.f / DIM);
    float var = Q * (1.f / DIM) - mu * mu;
    sm[0] = mu; sm[4] = rsqrtf(var + 1e-5f);
  }
  __syncthreads();
  const float mu = sm[0], rs = sm[4];
  float y0 = (v0 - mu) * rs * lg[t] + lb[t];
  float y1 = (v1 - mu) * rs * lg[t + 256] + lb[t + 256];
  xs[(size_t)row * DIM + t + 256] = y1;
  xsb[(size_t)row * DIM + t + 256] = f2bf(y1);
  if (s + 1 < SEQ) {
    xs[(size_t)(row + 1) * DIM + t] = y0;
    xsb[(size_t)(row + 1) * DIM + t] = f2bf(y0);
  }
  if (s == 0) { xs[(size_t)row * DIM + t] = 0.f; xsb[(size_t)row * DIM + t] = 0; }
}

// ---------------- weight transpose f32 [K][N] -> bf16 [rowOff+n][dstLD] ----------------
__global__ __launch_bounds__(256) void k_trw(const float* __restrict__ src, u16* __restrict__ dst,
    int N, int dstLD, int rowOff) {
  __shared__ u16 T[64][66];
  const int t = threadIdx.x;
  const int k0 = blockIdx.x * 64, n0 = blockIdx.y * 64;
  #pragma unroll
  for (int i = 0; i < 16; ++i) {
    int idx = t + 256 * i;
    int r = idx >> 6, c = idx & 63;
    T[c][r] = f2bf(src[(size_t)(k0 + r) * N + n0 + c]);
  }
  __syncthreads();
  #pragma unroll
  for (int i = 0; i < 16; ++i) {
    int idx = t + 256 * i;
    int r = idx >> 6, c = idx & 63;
    dst[(size_t)(rowOff + n0 + r) * dstLD + k0 + c] = T[r][c];
  }
}

// ---------------- HIDT [bg][e=512][j=256] -> HIDR [bg*256+j][512] (bf16) ----------------
__global__ __launch_bounds__(256) void k_trh(const u16* __restrict__ hidt, u16* __restrict__ hidr) {
  __shared__ u16 T[64][66];
  const int t = threadIdx.x;
  const int j0 = blockIdx.x * 64;
  const int e0 = blockIdx.y * 64;
  const int bg = blockIdx.z;
  #pragma unroll
  for (int i = 0; i < 16; ++i) {
    int idx = t + 256 * i; int r = idx >> 6, c = idx & 63;
    T[c][r] = hidt[((size_t)bg * 512 + e0 + r) * 256 + j0 + c];
  }
  __syncthreads();
  #pragma unroll
  for (int i = 0; i < 16; ++i) {
    int idx = t + 256 * i; int r = idx >> 6, c = idx & 63;
    hidr[((size_t)bg * 256 + j0 + r) * 512 + e0 + c] = T[r][c];
  }
}

// ---------------- Kernel 2: m97-style MFMA GEMM xsb @ [w_qk | w_hidden | w_gate] ----------------
__global__ __launch_bounds__(256, 3) void k_gemm1m(const u16* __restrict__ xsb,
    const u16* __restrict__ w1t, u16* __restrict__ qk, u16* __restrict__ hidt,
    u16* __restrict__ gate, u16* __restrict__ xg) {
  __shared__ u16 As[128 * 64];
  __shared__ u16 Bs[128 * 64];
  const int t = threadIdx.x;
  const int blk = blockIdx.x;                 // 3328 = 8 XCD x 32 m x 13 n
  const int xcd = blk & 7;
  const int loc = blk >> 3;                   // 0..415
  const int m0 = (xcd * 32 + loc / 13) * 128;
  const int n0 = (loc % 13) * 128;
  const int w = t >> 6, l = t & 63, lr = l & 15, lq = l >> 4;
  const int wr = (w >> 1) * 64, wc = (w & 1) * 64;
  const int rI = l >> 3;                      // row within 8-row issue
  const int c8 = (l & 7) ^ rI;                // pre-swizzled source col8
  const int slotA = lq ^ (lr & 7);            // read slot, kk=0 half
  const int slotB = (4 + lq) ^ (lr & 7);      // read slot, kk=32 half
  f32x4 acc[4][4];
  #pragma unroll
  for (int i = 0; i < 4; ++i)
    #pragma unroll
    for (int j = 0; j < 4; ++j) acc[i][j] = (f32x4){0.f, 0.f, 0.f, 0.f};
  for (int tt = 0; tt < 8; ++tt) {
    const int k0 = tt * 64;
    #pragma unroll
    for (int i = 0; i < 4; ++i) {
      const int br = w * 32 + i * 8;
      gl_lds16(xsb + (size_t)(m0 + br + rI) * 512 + k0 + c8 * 8, &As[br * 64]);
      gl_lds16(w1t + (size_t)(n0 + br + rI) * 512 + k0 + c8 * 8, &Bs[br * 64]);
    }
    __syncthreads();
    #pragma unroll
    for (int kk = 0; kk < 2; ++kk) {
      const int slot = kk ? slotB : slotA;
      s16x8 af[4], bf[4];
      #pragma unroll
      for (int fi = 0; fi < 4; ++fi) af[fi] = *(const s16x8*)&As[(wr + fi * 16 + lr) * 64 + slot * 8];
      #pragma unroll
      for (int fj = 0; fj < 4; ++fj) bf[fj] = *(const s16x8*)&Bs[(wc + fj * 16 + lr) * 64 + slot * 8];
      #pragma unroll
      for (int fi = 0; fi < 4; ++fi)
        #pragma unroll
        for (int fj = 0; fj < 4; ++fj)
          acc[fi][fj] = __builtin_amdgcn_mfma_f32_16x16x32_bf16(af[fi], bf[fj], acc[fi][fj], 0, 0, 0);
    }
    __syncthreads();
  }
  if (n0 == 0) {
    #pragma unroll
    for (int fi = 0; fi < 4; ++fi)
      #pragma unroll
      for (int fj = 0; fj < 4; ++fj) {
        const int n = wc + fj * 16 + lr;
        const int mb = m0 + wr + fi * 16 + lq * 4;
        #pragma unroll
        for (int r = 0; r < 4; ++r)
          qk[(size_t)(mb + r) * QKD + n] = f2bf(acc[fi][fj][r]);
      }
  } else if (n0 < 640) {
    const int bg = m0 >> 8;
    #pragma unroll
    for (int fi = 0; fi < 4; ++fi)
      #pragma unroll
      for (int fj = 0; fj < 4; ++fj) {
        const int e = n0 - 128 + wc + fj * 16 + lr;
        const int j0 = (m0 & 255) + wr + fi * 16 + lq * 4;
        ushort4 pk;
        pk.x = f2bf(acc[fi][fj][0]); pk.y = f2bf(acc[fi][fj][1]);
        pk.z = f2bf(acc[fi][fj][2]); pk.w = f2bf(acc[fi][fj][3]);
        *(ushort4*)(hidt + ((size_t)bg * 512 + e) * 256 + j0) = pk;
      }
  } else if (n0 < 1152) {
    #pragma unroll
    for (int fi = 0; fi < 4; ++fi)
      #pragma unroll
      for (int fj = 0; fj < 4; ++fj) {
        const int n = n0 - 640 + wc + fj * 16 + lr;
        const int mb = m0 + wr + fi * 16 + lq * 4;
        #pragma unroll
        for (int r = 0; r < 4; ++r)
          gate[(size_t)(mb + r) * HIDD + n] = f2bf(acc[fi][fj][r]);
      }
  } else {
    #pragma unroll
    for (int fi = 0; fi < 4; ++fi)
      #pragma unroll
      for (int fj = 0; fj < 4; ++fj) {
        const int n = n0 - 1152 + wc + fj * 16 + lr;
        const int mb = m0 + wr + fi * 16 + lq * 4;
        #pragma unroll
        for (int r = 0; r < 4; ++r)
          xg[(size_t)(mb + r) * HIDD + n] = f2bf(silu_f(acc[fi][fj][r]));
      }
  }
}

// ---------------- Kernel 3: fused qk_mean + per-j bias b[bg][h][j] ----------------
__global__ __launch_bounds__(256) void k_qkmb(const u16* __restrict__ qk,
    const float* __restrict__ g4, const float* __restrict__ b4,
    const float* __restrict__ g2, const float* __restrict__ b2,
    float* __restrict__ qm, float* __restrict__ bjs) {
  __shared__ float smQ[128];
  __shared__ float tmp[256];
  const int bg = blockIdx.x;
  const size_t grpRow = (size_t)bg * NPG;
  const int t = threadIdx.x;
  {
    const int c = t & 127, half = t >> 7;
    const u16* p = qk + (grpRow + half * 128) * QKD + c;
    float s = 0.f;
    for (int i = 0; i < 128; ++i) s += bf2f(p[(size_t)i * QKD]);
    tmp[t] = s;
  }
  __syncthreads();
  if (t < 128) {
    float m = (tmp[t] + tmp[t + 128]) * (1.f / NPG);
    smQ[t] = m;
    qm[bg * QKD + t] = m;
  }
  __syncthreads();
  const int h = t >> 6, l = t & 63;
  const bool sh = (h >= 2);
  const int cbase = (h & 1) << 6;
  const int dd = (l & 7) * 8;                 // this lane's 8-col slice
  float c[8];
  #pragma unroll
  for (int e = 0; e < 8; ++e) {
    int d = cbase + dd + e;
    float qmv = smQ[d];
    float qsc = qmv * g4[2 * QKD + d] + b4[2 * QKD + d];
    float qof = qmv * g4[d] + b4[d];
    float ksc = qmv * g4[3 * QKD + d] + b4[3 * QKD + d];
    float Oq, Sk;
    if (!sh) { Oq = qof; Sk = ksc; }
    else {
      float qso = qmv * g2[d] + b2[d];
      Oq = qof * qsc + qso;
      Sk = ksc * ksc;
    }
    c[e] = Oq * Sk;
  }
  float* bp = bjs + ((size_t)bg * 4 + h) * NPG;
  for (int jb = 0; jb < NPG; jb += 8) {
    int j = jb + (l >> 3);
    int src = sh ? (j ? j - 1 : 0) : j;
    const u16* row = qk + (grpRow + src) * QKD + cbase + dd;
    float s = 0.f;
    #pragma unroll
    for (int e = 0; e < 8; ++e) s += bf2f(row[e]) * c[e];
    s += __shfl_xor(s, 1); s += __shfl_xor(s, 2); s += __shfl_xor(s, 4);
    if ((l & 7) == 0) bp[j] = s;
  }
}

// ---------------- Kernel 4: 8-wave paired-tile decomposed attention ----------------
// Block = (bg, pair p): 512 threads = 8 waves; wave w = (tile = w>>2 ? 15-p : p, head = w&3).
// Each wave owns ONE tile's state (no register doubling); V octants staged ONCE per
// block (sized to the larger tile's causal bound, which covers the smaller).
__global__ __launch_bounds__(512, 8) void k_attn(const u16* __restrict__ qk,
    const float* __restrict__ qm, const float* __restrict__ g4, const float* __restrict__ b4,
    const float* __restrict__ bjs, const u16* __restrict__ hidt,
    const u16* __restrict__ gate, u16* __restrict__ out4) {
  __shared__ u16 Vs[64][264];                 // one 64-e x (causal j) octant of V^T
  const int t = threadIdx.x;
  const int l = t & 63;
  const int w8 = t >> 6;                      // 0..7
  const int h = w8 & 3;
  const bool sh = (h >= 2);
  const int blk = blockIdx.x;                 // 1024 = 8 XCD x 16 bg x 8 pair
  const int xcd = blk & 7;
  const int bb = blk >> 3;                    // 0..127 per XCD
  const int bg = xcd * 16 + (bb >> 3);
  const int pair = bb & 7;
  const int iw = (w8 >> 2) ? (15 - pair) : pair;
  const size_t grpRow = (size_t)bg * NPG;
  const int cbase = (h & 1) << 6;
  const int lr = l & 15, lq = l >> 4;
  const int cA = cbase + 8 * lq;
  const int ntmax = iw, jtmax = iw >> 1;
  const int jtmaxStage = (15 - pair) >> 1;    // block-uniform staging bound (covers both)
  const int irow = iw * 16 + lr;
  // ---- W = Sq*Sk for this lane's 16 cols ----
  const float* qmp = qm + bg * QKD;
  float4 qmA = LD4(qmp, cA),      qmB = LD4(qmp, cA + 4);
  float4 qmC = LD4(qmp, cA + 32), qmD = LD4(qmp, cA + 36);
  float4 wA = mul4(fma4(qmA, LD4(g4, 2*QKD+cA),    LD4(b4, 2*QKD+cA)),
                   fma4(qmA, LD4(g4, 3*QKD+cA),    LD4(b4, 3*QKD+cA)));
  float4 wB = mul4(fma4(qmB, LD4(g4, 2*QKD+cA+4),  LD4(b4, 2*QKD+cA+4)),
                   fma4(qmB, LD4(g4, 3*QKD+cA+4),  LD4(b4, 3*QKD+cA+4)));
  float4 wC = mul4(fma4(qmC, LD4(g4, 2*QKD+cA+32), LD4(b4, 2*QKD+cA+32)),
                   fma4(qmC, LD4(g4, 3*QKD+cA+32), LD4(b4, 3*QKD+cA+32)));
  float4 wD = mul4(fma4(qmD, LD4(g4, 2*QKD+cA+36), LD4(b4, 2*QKD+cA+36)),
                   fma4(qmD, LD4(g4, 3*QKD+cA+36), LD4(b4, 3*QKD+cA+36)));
  if (sh) { wA = mul4(wA, wA); wB = mul4(wB, wB); wC = mul4(wC, wC); wD = mul4(wD, wD); }
  const float scl = 0.17677669529663687f;     // 1/sqrt(32)
  // ---- Q fragment (B-operand: col = lr = q-row i): raw qk row * W ----
  const int qsrc = sh ? (irow ? irow - 1 : 0) : irow;
  const u16* qrow = qk + (grpRow + qsrc) * QKD + cA;
  s16x8 qb0 = mul8(*(const s16x8*)qrow,        wA, wB);
  s16x8 qb1 = mul8(*(const s16x8*)(qrow + 32), wC, wD);
  // ---- QK^T (A = RAW qk row-tile, causally bounded) ----
  f32x4 sfr[16];
  #pragma unroll
  for (int nt = 0; nt < 16; ++nt) if (nt <= ntmax) {
    const int jr = nt * 16 + lr;
    const int ksrc = sh ? (jr ? jr - 1 : 0) : jr;
    const u16* kr = qk + (grpRow + ksrc) * QKD + cA;
    s16x8 ka0 = *(const s16x8*)kr;
    s16x8 ka1 = *(const s16x8*)(kr + 32);
    f32x4 c = {0.f, 0.f, 0.f, 0.f};
    c = __builtin_amdgcn_mfma_f32_16x16x32_bf16(ka0, qb0, c, 0, 0, 0);
    c = __builtin_amdgcn_mfma_f32_16x16x32_bf16(ka1, qb1, c, 0, 0, 0);
    sfr[nt] = c;
  }
  // ---- add per-j bias ----
  const float* bp = bjs + ((size_t)bg * 4 + h) * NPG;
  #pragma unroll
  for (int nt = 0; nt < 16; ++nt) if (nt <= ntmax) {
    float4 bv = LD4(bp, nt * 16 + lq * 4);
    f32x4 c = sfr[nt];
    c[0] += bv.x; c[1] += bv.y; c[2] += bv.z; c[3] += bv.w;
    sfr[nt] = c;
  }
  // ---- softmax over j for this lane's row ----
  float mx = -3.4e38f;
  #pragma unroll
  for (int nt = 0; nt < 16; ++nt) if (nt <= ntmax) {
    #pragma unroll
    for (int r = 0; r < 4; ++r) {
      int j = nt * 16 + lq * 4 + r;
      if (j <= irow) mx = fmaxf(mx, sfr[nt][r] * scl);
    }
  }
  mx = fmaxf(mx, __shfl_xor(mx, 16));
  mx = fmaxf(mx, __shfl_xor(mx, 32));
  float sum = 0.f;
  u32 p01[16], p23[16];
  #pragma unroll
  for (int nt = 0; nt < 16; ++nt) { p01[nt] = 0u; p23[nt] = 0u; }
  #pragma unroll
  for (int nt = 0; nt < 16; ++nt) if (nt <= ntmax) {
    int j = nt * 16 + lq * 4;
    float e0 = (j + 0 <= irow) ? __expf(sfr[nt][0] * scl - mx) : 0.f;
    float e1 = (j + 1 <= irow) ? __expf(sfr[nt][1] * scl - mx) : 0.f;
    float e2 = (j + 2 <= irow) ? __expf(sfr[nt][2] * scl - mx) : 0.f;
    float e3 = (j + 3 <= irow) ? __expf(sfr[nt][3] * scl - mx) : 0.f;
    sum += (e0 + e1) + (e2 + e3);
    p01[nt] = (u32)f2bf(e0) | ((u32)f2bf(e1) << 16);
    p23[nt] = (u32)f2bf(e2) | ((u32)f2bf(e3) << 16);
  }
  sum += __shfl_xor(sum, 16);
  sum += __shfl_xor(sum, 32);
  const float inv = 1.f / sum;
  // ---- build P^T B-frags via in-wave shuffles ----
  const int srcA = (l & 15) | ((l & 16) << 1);   // lr + 32*(lq&1)
  const int srcB = srcA + 16;
  const bool hi = (l >= 32);
  s16x8 bfr[8];
  #pragma unroll
  for (int jt = 0; jt < 8; ++jt) if (jt <= jtmax) {
    u32 a0 = __shfl((int)p01[2 * jt], srcA), a1 = __shfl((int)p23[2 * jt], srcA);
    u32 a2 = __shfl((int)p01[2 * jt], srcB), a3 = __shfl((int)p23[2 * jt], srcB);
    u32 b0 = __shfl((int)p01[2 * jt + 1], srcA), b1 = __shfl((int)p23[2 * jt + 1], srcA);
    u32 b2 = __shfl((int)p01[2 * jt + 1], srcB), b3 = __shfl((int)p23[2 * jt + 1], srcB);
    union { u32 u[4]; s16x8 v; } bb2;
    bb2.u[0] = hi ? b0 : a0; bb2.u[1] = hi ? b1 : a1;
    bb2.u[2] = hi ? b2 : a2; bb2.u[3] = hi ? b3 : a3;
    bfr[jt] = bb2.v;
  }
  // ---- PV over 8 e-octants: stage once per block (both tiles share the LDS tile) ----
  const u16* vtb = hidt + (size_t)bg * (512 * 256);
  const size_t srow = grpRow + irow;
  const u16* gp = gate + srow * HIDD;
  u16* op = out4 + srow * 2048 + ((size_t)h << 9);
  const int vr = t >> 3, vc = t & 7;          // 64 rows x 8 col8 per pass
  const int nj8 = (jtmaxStage + 1) * 4;       // col8 count to stage
  for (int oct = 0; oct < 8; ++oct) {
    __syncthreads();                          // previous octant fully consumed
    const u16* src = vtb + (size_t)oct * 64 * 256;
    for (int cc = vc; cc < nj8; cc += 8)
      *(uint4*)&Vs[vr][cc * 8] = *(const uint4*)(src + (size_t)vr * 256 + cc * 8);
    __syncthreads();
    f32x4 acc[4];
    #pragma unroll
    for (int ef = 0; ef < 4; ++ef) acc[ef] = (f32x4){0.f, 0.f, 0.f, 0.f};
    #pragma unroll
    for (int jt = 0; jt < 8; ++jt) if (jt <= jtmax) {
      __builtin_amdgcn_s_setprio(1);
      #pragma unroll
      for (int ef = 0; ef < 4; ++ef) {
        s16x8 va = *(const s16x8*)&Vs[ef * 16 + lr][jt * 32 + 8 * lq];
        acc[ef] = __builtin_amdgcn_mfma_f32_16x16x32_bf16(va, bfr[jt], acc[ef], 0, 0, 0);
      }
      __builtin_amdgcn_s_setprio(0);
    }
    #pragma unroll
    for (int ef = 0; ef < 4; ++ef) {
      const int e = oct * 64 + ef * 16 + lq * 4;
      ushort4 gu = *(const ushort4*)(gp + e);
      ushort4 ov;
      ov.x = f2bf(silu_fast(acc[ef][0] * inv) * bf2f(gu.x));
      ov.y = f2bf(silu_fast(acc[ef][1] * inv) * bf2f(gu.y));
      ov.z = f2bf(silu_fast(acc[ef][2] * inv) * bf2f(gu.z));
      ov.w = f2bf(silu_fast(acc[ef][3] * inv) * bf2f(gu.w));
      *(ushort4*)(op + e) = ov;
    }
  }
}

// ---------------- Kernel 5: m97-style MFMA GEMM residual(2560) @ w_out + epilogue ----------------
__global__ __launch_bounds__(256, 3) void k_gemm2m(const u16* __restrict__ hidr,
    const u16* __restrict__ out4, const u16* __restrict__ wt,
    const u16* __restrict__ xg, float* __restrict__ out) {
  __shared__ u16 As[128 * 64];
  __shared__ u16 Bs[128 * 64];
  const int t = threadIdx.x;
  const int blk = blockIdx.x;                 // 1024 = 8 XCD x 32 m x 4 n
  const int xcd = blk & 7;
  const int loc = blk >> 3;                   // 0..127
  const int m0 = (xcd * 32 + (loc >> 2)) * 128;
  const int n0 = (loc & 3) * 128;
  const int w = t >> 6, l = t & 63, lr = l & 15, lq = l >> 4;
  const int wr = (w >> 1) * 64, wc = (w & 1) * 64;
  const int rI = l >> 3;
  const int c8 = (l & 7) ^ rI;
  const int slotA = lq ^ (lr & 7);
  const int slotB = (4 + lq) ^ (lr & 7);
  f32x4 acc[4][4];
  #pragma unroll
  for (int i = 0; i < 4; ++i)
    #pragma unroll
    for (int j = 0; j < 4; ++j) acc[i][j] = (f32x4){0.f, 0.f, 0.f, 0.f};
  for (int tt = 0; tt < 40; ++tt) {
    const int k0 = tt * 64;
    const u16* ab; size_t ald; int ko;
    if (k0 < 512) { ab = hidr; ald = 512;  ko = k0; }
    else          { ab = out4; ald = 2048; ko = k0 - 512; }
    #pragma unroll
    for (int i = 0; i < 4; ++i) {
      const int br = w * 32 + i * 8;
      gl_lds16(ab + (size_t)(m0 + br + rI) * ald + ko + c8 * 8, &As[br * 64]);
      gl_lds16(wt + (size_t)(n0 + br + rI) * 2560 + k0 + c8 * 8, &Bs[br * 64]);
    }
    __syncthreads();
    #pragma unroll
    for (int kk = 0; kk < 2; ++kk) {
      const int slot = kk ? slotB : slotA;
      s16x8 af[4], bf[4];
      #pragma unroll
      for (int fi = 0; fi < 4; ++fi) af[fi] = *(const s16x8*)&As[(wr + fi * 16 + lr) * 64 + slot * 8];
      #pragma unroll
      for (int fj = 0; fj < 4; ++fj) bf[fj] = *(const s16x8*)&Bs[(wc + fj * 16 + lr) * 64 + slot * 8];
      #pragma unroll
      for (int fi = 0; fi < 4; ++fi)
        #pragma unroll
        for (int fj = 0; fj < 4; ++fj)
          acc[fi][fj] = __builtin_amdgcn_mfma_f32_16x16x32_bf16(af[fi], bf[fj], acc[fi][fj], 0, 0, 0);
    }
    __syncthreads();
  }
  #pragma unroll
  for (int fi = 0; fi < 4; ++fi)
    #pragma unroll
    for (int fj = 0; fj < 4; ++fj) {
      const int n = n0 + wc + fj * 16 + lr;
      const int mb = m0 + wr + fi * 16 + lq * 4;
      #pragma unroll
      for (int r = 0; r < 4; ++r) {
        const size_t idx = (size_t)(mb + r) * DIM + n;
        out[idx] = acc[fi][fj][r] * bf2f(xg[idx]) + out[idx];   // out holds xs (in-place)
      }
    }
}

extern "C" void kernel_launch(void* const* d_in, const int* in_sizes, int n_in,
                              void* d_out, int out_size, void* d_ws, size_t ws_size,
                              hipStream_t stream) {
  const float* x        = (const float*)d_in[0];
  const float* lg       = (const float*)d_in[1];
  const float* lb       = (const float*)d_in[2];
  const float* w_qk     = (const float*)d_in[3];
  const float* g4       = (const float*)d_in[4];
  const float* b4       = (const float*)d_in[5];
  const float* g2       = (const float*)d_in[6];
  const float* b2       = (const float*)d_in[7];
  const float* w_hidden = (const float*)d_in[8];
  const float* w_gate   = (const float*)d_in[9];
  const float* w_out    = (const float*)d_in[10];
  // ws layout (bytes), total 248,184,832 (<= R2-proven 251,723,776):
  //   QM   f32  @ 0              65,536
  //   HIDT bf16 @ 65,536     33,554,432   [bg][e][j]
  //   GATE bf16 @ 33,619,968 33,554,432   (HIDR overlays after attn)
  //   XG   bf16 @ 67,174,400 33,554,432
  //   QK   bf16 @ 100,728,832 8,388,608
  //   W1T  bf16 @ 109,117,440 1,703,936   [1664][512]
  //   WT   bf16 @ 110,821,376 2,621,440   [512][2560]
  //   OUT4 bf16 @ 113,442,816 134,217,728
  //   BJS  f32  @ 247,660,544    524,288  [bg][h][256] softmax bias
  // Overlays: HIDR (33,554,432) @ GATE  — written by k_trh AFTER attn (GATE dead).
  //           XSB  (33,554,432) @ OUT4  — written by k_ln, read by gemm1m; OUT4 is
  //                                       written by attn strictly AFTER gemm1m reads.
  // xs (f32) lives in d_out, overwritten in-place by k_gemm2m epilogue.
  if (ws_size < 248184832ull) return;
  char* ws = (char*)d_ws;
  float* QM   = (float*)(ws + 0);
  u16*   HIDT = (u16*)  (ws + 65536);
  u16*   GATE = (u16*)  (ws + 33619968);
  u16*   XG   = (u16*)  (ws + 67174400);
  u16*   QKb  = (u16*)  (ws + 100728832);
  u16*   W1T  = (u16*)  (ws + 109117440);
  u16*   WT   = (u16*)  (ws + 110821376);
  u16*   OUT4 = (u16*)  (ws + 113442816);
  u16*   XSB  = (u16*)  (ws + 113442816);   // overlay on OUT4 (pre-attn lifetime)
  u16*   HIDR = (u16*)  (ws + 33619968);    // overlay on GATE (post-attn)
  float* BJS  = (float*)(ws + 247660544);
  float* XS   = (float*)d_out;
  float* OUT  = (float*)d_out;

  k_ln<<<BB * SEQ, 256, 0, stream>>>(x, lg, lb, XS, XSB);
  k_trw<<<dim3(8, 2),  256, 0, stream>>>(w_qk,     W1T, 128,  512,  0);
  k_trw<<<dim3(8, 16), 256, 0, stream>>>(w_hidden, W1T, 1024, 512,  128);
  k_trw<<<dim3(8, 8),  256, 0, stream>>>(w_gate,   W1T, 512,  512,  1152);
  k_trw<<<dim3(40, 8), 256, 0, stream>>>(w_out,    WT,  512,  2560, 0);
  k_gemm1m<<<3328, 256, 0, stream>>>(XSB, W1T, QKb, HIDT, GATE, XG);
  k_qkmb<<<BB * GG, 256, 0, stream>>>(QKb, g4, b4, g2, b2, QM, BJS);
  k_attn<<<BB * GG * 8, 512, 0, stream>>>(QKb, QM, g4, b4, BJS, HIDT, GATE, OUT4);
  k_trh<<<dim3(4, 8, 128), 256, 0, stream>>>(HIDT, HIDR);
  k_gemm2m<<<1024, 256, 0, stream>>>(HIDR, OUT4, WT, XG, OUT);
}

// Round 18
// 386.827 us; speedup vs baseline: 1.3016x; 1.0820x over previous
//
#include <hip/hip_runtime.h>
#include <hip/hip_bf16.h>
#include <math.h>

#define BB 4
#define SEQ 8192
#define DIM 512
#define GG 32
#define NPG 256
#define QKD 128
#define HIDD 512

typedef unsigned short u16;
typedef unsigned int u32;

using s16x8 = __attribute__((ext_vector_type(8))) short;
using f32x4 = __attribute__((ext_vector_type(4))) float;

__device__ __forceinline__ float bf2f(u16 u) { return __uint_as_float(((u32)u) << 16); }
__device__ __forceinline__ u16 f2bf(float f) {
  u32 b = __float_as_uint(f);
  return (u16)((b + 0x7FFFu + ((b >> 16) & 1u)) >> 16);
}
__device__ __forceinline__ float silu_f(float x) { return x / (1.f + expf(-x)); }
__device__ __forceinline__ float silu_fast(float x) { return x / (1.f + __expf(-x)); }
__device__ __forceinline__ float4 fma4(float4 a, float4 b, float4 c) {
  return make_float4(a.x*b.x+c.x, a.y*b.y+c.y, a.z*b.z+c.z, a.w*b.w+c.w);
}
__device__ __forceinline__ float4 mul4(float4 a, float4 b) {
  return make_float4(a.x*b.x, a.y*b.y, a.z*b.z, a.w*b.w);
}
#define LD4(p, off) (*(const float4*)((p) + (off)))

// async global->LDS, 16B per lane; LDS dest = wave-uniform base + lane*16
__device__ __forceinline__ void gl_lds16(const u16* g, u16* l) {
  __builtin_amdgcn_global_load_lds((const __attribute__((address_space(1))) void*)g,
                                   (__attribute__((address_space(3))) void*)l, 16, 0, 0);
}

// elementwise scale 8 bf16 by f32 params: out = v*s
__device__ __forceinline__ s16x8 mul8(s16x8 v, float4 s0, float4 s1) {
  union U { s16x8 x; u16 u[8]; };
  U in; in.x = v; U r;
  r.u[0] = f2bf(bf2f(in.u[0]) * s0.x);
  r.u[1] = f2bf(bf2f(in.u[1]) * s0.y);
  r.u[2] = f2bf(bf2f(in.u[2]) * s0.z);
  r.u[3] = f2bf(bf2f(in.u[3]) * s0.w);
  r.u[4] = f2bf(bf2f(in.u[4]) * s1.x);
  r.u[5] = f2bf(bf2f(in.u[5]) * s1.y);
  r.u[6] = f2bf(bf2f(in.u[6]) * s1.z);
  r.u[7] = f2bf(bf2f(in.u[7]) * s1.w);
  return r.x;
}

// ---------------- Kernel 1: LayerNorm + global seq-shift scatter (f32 + bf16 copies) ----------------
__global__ __launch_bounds__(256) void k_ln(const float* __restrict__ x,
    const float* __restrict__ lg, const float* __restrict__ lb,
    float* __restrict__ xs, u16* __restrict__ xsb) {
  const int row = blockIdx.x;               // b*SEQ + s
  const int s = row & (SEQ - 1);
  const int t = threadIdx.x;
  const float* xr = x + (size_t)row * DIM;
  float v0 = xr[t], v1 = xr[t + 256];
  float sum = v0 + v1, sq = v0 * v0 + v1 * v1;
  #pragma unroll
  for (int o = 32; o; o >>= 1) { sum += __shfl_down(sum, o); sq += __shfl_down(sq, o); }
  __shared__ float sm[8];
  const int w = t >> 6;
  if ((t & 63) == 0) { sm[w] = sum; sm[4 + w] = sq; }
  __syncthreads();
  if (t == 0) {
    float S = sm[0] + sm[1] + sm[2] + sm[3];
    float Q = sm[4] + sm[5] + sm[6] + sm[7];
    float mu = S * (1.f / DIM);
    float var = Q * (1.f / DIM) - mu * mu;
    sm[0] = mu; sm[4] = rsqrtf(var + 1e-5f);
  }
  __syncthreads();
  const float mu = sm[0], rs = sm[4];
  float y0 = (v0 - mu) * rs * lg[t] + lb[t];
  float y1 = (v1 - mu) * rs * lg[t + 256] + lb[t + 256];
  xs[(size_t)row * DIM + t + 256] = y1;
  xsb[(size_t)row * DIM + t + 256] = f2bf(y1);
  if (s + 1 < SEQ) {
    xs[(size_t)(row + 1) * DIM + t] = y0;
    xsb[(size_t)(row + 1) * DIM + t] = f2bf(y0);
  }
  if (s == 0) { xs[(size_t)row * DIM + t] = 0.f; xsb[(size_t)row * DIM + t] = 0; }
}

// ---------------- weight transpose f32 [K][N] -> bf16 [rowOff+n][dstLD] ----------------
__global__ __launch_bounds__(256) void k_trw(const float* __restrict__ src, u16* __restrict__ dst,
    int N, int dstLD, int rowOff) {
  __shared__ u16 T[64][66];
  const int t = threadIdx.x;
  const int k0 = blockIdx.x * 64, n0 = blockIdx.y * 64;
  #pragma unroll
  for (int i = 0; i < 16; ++i) {
    int idx = t + 256 * i;
    int r = idx >> 6, c = idx & 63;
    T[c][r] = f2bf(src[(size_t)(k0 + r) * N + n0 + c]);
  }
  __syncthreads();
  #pragma unroll
  for (int i = 0; i < 16; ++i) {
    int idx = t + 256 * i;
    int r = idx >> 6, c = idx & 63;
    dst[(size_t)(rowOff + n0 + r) * dstLD + k0 + c] = T[r][c];
  }
}

// ---------------- HIDT [bg][e=512][j=256] -> HIDR [bg*256+j][512] (bf16) ----------------
__global__ __launch_bounds__(256) void k_trh(const u16* __restrict__ hidt, u16* __restrict__ hidr) {
  __shared__ u16 T[64][66];
  const int t = threadIdx.x;
  const int j0 = blockIdx.x * 64;
  const int e0 = blockIdx.y * 64;
  const int bg = blockIdx.z;
  #pragma unroll
  for (int i = 0; i < 16; ++i) {
    int idx = t + 256 * i; int r = idx >> 6, c = idx & 63;
    T[c][r] = hidt[((size_t)bg * 512 + e0 + r) * 256 + j0 + c];
  }
  __syncthreads();
  #pragma unroll
  for (int i = 0; i < 16; ++i) {
    int idx = t + 256 * i; int r = idx >> 6, c = idx & 63;
    hidr[((size_t)bg * 256 + j0 + r) * 512 + e0 + c] = T[r][c];
  }
}

// ---------------- Kernel 2: m97-style MFMA GEMM xsb @ [w_qk | w_hidden | w_gate] ----------------
__global__ __launch_bounds__(256, 4) void k_gemm1m(const u16* __restrict__ xsb,
    const u16* __restrict__ w1t, u16* __restrict__ qk, u16* __restrict__ hidt,
    u16* __restrict__ gate, u16* __restrict__ xg) {
  __shared__ u16 As[128 * 64];
  __shared__ u16 Bs[128 * 64];
  const int t = threadIdx.x;
  const int blk = blockIdx.x;                 // 3328 = 8 XCD x 32 m x 13 n
  const int xcd = blk & 7;
  const int loc = blk >> 3;                   // 0..415
  const int m0 = (xcd * 32 + loc / 13) * 128;
  const int n0 = (loc % 13) * 128;
  const int w = t >> 6, l = t & 63, lr = l & 15, lq = l >> 4;
  const int wr = (w >> 1) * 64, wc = (w & 1) * 64;
  const int rI = l >> 3;                      // row within 8-row issue
  const int c8 = (l & 7) ^ rI;                // pre-swizzled source col8
  const int slotA = lq ^ (lr & 7);            // read slot, kk=0 half
  const int slotB = (4 + lq) ^ (lr & 7);      // read slot, kk=32 half
  f32x4 acc[4][4];
  #pragma unroll
  for (int i = 0; i < 4; ++i)
    #pragma unroll
    for (int j = 0; j < 4; ++j) acc[i][j] = (f32x4){0.f, 0.f, 0.f, 0.f};
  for (int tt = 0; tt < 8; ++tt) {
    const int k0 = tt * 64;
    #pragma unroll
    for (int i = 0; i < 4; ++i) {
      const int br = w * 32 + i * 8;
      gl_lds16(xsb + (size_t)(m0 + br + rI) * 512 + k0 + c8 * 8, &As[br * 64]);
      gl_lds16(w1t + (size_t)(n0 + br + rI) * 512 + k0 + c8 * 8, &Bs[br * 64]);
    }
    __syncthreads();
    #pragma unroll
    for (int kk = 0; kk < 2; ++kk) {
      const int slot = kk ? slotB : slotA;
      s16x8 af[4], bf[4];
      #pragma unroll
      for (int fi = 0; fi < 4; ++fi) af[fi] = *(const s16x8*)&As[(wr + fi * 16 + lr) * 64 + slot * 8];
      #pragma unroll
      for (int fj = 0; fj < 4; ++fj) bf[fj] = *(const s16x8*)&Bs[(wc + fj * 16 + lr) * 64 + slot * 8];
      #pragma unroll
      for (int fi = 0; fi < 4; ++fi)
        #pragma unroll
        for (int fj = 0; fj < 4; ++fj)
          acc[fi][fj] = __builtin_amdgcn_mfma_f32_16x16x32_bf16(af[fi], bf[fj], acc[fi][fj], 0, 0, 0);
    }
    __syncthreads();
  }
  if (n0 == 0) {
    #pragma unroll
    for (int fi = 0; fi < 4; ++fi)
      #pragma unroll
      for (int fj = 0; fj < 4; ++fj) {
        const int n = wc + fj * 16 + lr;
        const int mb = m0 + wr + fi * 16 + lq * 4;
        #pragma unroll
        for (int r = 0; r < 4; ++r)
          qk[(size_t)(mb + r) * QKD + n] = f2bf(acc[fi][fj][r]);
      }
  } else if (n0 < 640) {
    const int bg = m0 >> 8;
    #pragma unroll
    for (int fi = 0; fi < 4; ++fi)
      #pragma unroll
      for (int fj = 0; fj < 4; ++fj) {
        const int e = n0 - 128 + wc + fj * 16 + lr;
        const int j0 = (m0 & 255) + wr + fi * 16 + lq * 4;
        ushort4 pk;
        pk.x = f2bf(acc[fi][fj][0]); pk.y = f2bf(acc[fi][fj][1]);
        pk.z = f2bf(acc[fi][fj][2]); pk.w = f2bf(acc[fi][fj][3]);
        *(ushort4*)(hidt + ((size_t)bg * 512 + e) * 256 + j0) = pk;
      }
  } else if (n0 < 1152) {
    #pragma unroll
    for (int fi = 0; fi < 4; ++fi)
      #pragma unroll
      for (int fj = 0; fj < 4; ++fj) {
        const int n = n0 - 640 + wc + fj * 16 + lr;
        const int mb = m0 + wr + fi * 16 + lq * 4;
        #pragma unroll
        for (int r = 0; r < 4; ++r)
          gate[(size_t)(mb + r) * HIDD + n] = f2bf(acc[fi][fj][r]);
      }
  } else {
    #pragma unroll
    for (int fi = 0; fi < 4; ++fi)
      #pragma unroll
      for (int fj = 0; fj < 4; ++fj) {
        const int n = n0 - 1152 + wc + fj * 16 + lr;
        const int mb = m0 + wr + fi * 16 + lq * 4;
        #pragma unroll
        for (int r = 0; r < 4; ++r)
          xg[(size_t)(mb + r) * HIDD + n] = f2bf(silu_f(acc[fi][fj][r]));
      }
  }
}

// ---------------- Kernel 3: fused qk_mean + per-j bias b[bg][h][j] ----------------
__global__ __launch_bounds__(256) void k_qkmb(const u16* __restrict__ qk,
    const float* __restrict__ g4, const float* __restrict__ b4,
    const float* __restrict__ g2, const float* __restrict__ b2,
    float* __restrict__ qm, float* __restrict__ bjs) {
  __shared__ float smQ[128];
  __shared__ float tmp[256];
  const int bg = blockIdx.x;
  const size_t grpRow = (size_t)bg * NPG;
  const int t = threadIdx.x;
  {
    const int c = t & 127, half = t >> 7;
    const u16* p = qk + (grpRow + half * 128) * QKD + c;
    float s = 0.f;
    for (int i = 0; i < 128; ++i) s += bf2f(p[(size_t)i * QKD]);
    tmp[t] = s;
  }
  __syncthreads();
  if (t < 128) {
    float m = (tmp[t] + tmp[t + 128]) * (1.f / NPG);
    smQ[t] = m;
    qm[bg * QKD + t] = m;
  }
  __syncthreads();
  const int h = t >> 6, l = t & 63;
  const bool sh = (h >= 2);
  const int cbase = (h & 1) << 6;
  const int dd = (l & 7) * 8;                 // this lane's 8-col slice
  float c[8];
  #pragma unroll
  for (int e = 0; e < 8; ++e) {
    int d = cbase + dd + e;
    float qmv = smQ[d];
    float qsc = qmv * g4[2 * QKD + d] + b4[2 * QKD + d];
    float qof = qmv * g4[d] + b4[d];
    float ksc = qmv * g4[3 * QKD + d] + b4[3 * QKD + d];
    float Oq, Sk;
    if (!sh) { Oq = qof; Sk = ksc; }
    else {
      float qso = qmv * g2[d] + b2[d];
      Oq = qof * qsc + qso;
      Sk = ksc * ksc;
    }
    c[e] = Oq * Sk;
  }
  float* bp = bjs + ((size_t)bg * 4 + h) * NPG;
  for (int jb = 0; jb < NPG; jb += 8) {
    int j = jb + (l >> 3);
    int src = sh ? (j ? j - 1 : 0) : j;
    const u16* row = qk + (grpRow + src) * QKD + cbase + dd;
    float s = 0.f;
    #pragma unroll
    for (int e = 0; e < 8; ++e) s += bf2f(row[e]) * c[e];
    s += __shfl_xor(s, 1); s += __shfl_xor(s, 2); s += __shfl_xor(s, 4);
    if ((l & 7) == 0) bp[j] = s;
  }
}

// ---------------- Kernel 4: 8-wave paired-tile decomposed attention ----------------
// Block = (bg, pair p): 512 threads = 8 waves; wave w = (tile = w>>2 ? 15-p : p, head = w&3).
// Each wave owns ONE tile's state; V octants staged ONCE per block.
__global__ __launch_bounds__(512, 4) void k_attn(const u16* __restrict__ qk,
    const float* __restrict__ qm, const float* __restrict__ g4, const float* __restrict__ b4,
    const float* __restrict__ bjs, const u16* __restrict__ hidt,
    const u16* __restrict__ gate, u16* __restrict__ out4) {
  __shared__ u16 Vs[64][264];                 // one 64-e x (causal j) octant of V^T
  const int t = threadIdx.x;
  const int l = t & 63;
  const int w8 = t >> 6;                      // 0..7
  const int h = w8 & 3;
  const bool sh = (h >= 2);
  const int blk = blockIdx.x;                 // 1024 = 8 XCD x 16 bg x 8 pair
  const int xcd = blk & 7;
  const int bb = blk >> 3;                    // 0..127 per XCD
  const int bg = xcd * 16 + (bb >> 3);
  const int pair = bb & 7;
  const int iw = (w8 >> 2) ? (15 - pair) : pair;
  const size_t grpRow = (size_t)bg * NPG;
  const int cbase = (h & 1) << 6;
  const int lr = l & 15, lq = l >> 4;
  const int cA = cbase + 8 * lq;
  const int ntmax = iw, jtmax = iw >> 1;
  const int jtmaxStage = (15 - pair) >> 1;    // block-uniform staging bound (covers both)
  const int irow = iw * 16 + lr;
  // ---- W = Sq*Sk for this lane's 16 cols ----
  const float* qmp = qm + bg * QKD;
  float4 qmA = LD4(qmp, cA),      qmB = LD4(qmp, cA + 4);
  float4 qmC = LD4(qmp, cA + 32), qmD = LD4(qmp, cA + 36);
  float4 wA = mul4(fma4(qmA, LD4(g4, 2*QKD+cA),    LD4(b4, 2*QKD+cA)),
                   fma4(qmA, LD4(g4, 3*QKD+cA),    LD4(b4, 3*QKD+cA)));
  float4 wB = mul4(fma4(qmB, LD4(g4, 2*QKD+cA+4),  LD4(b4, 2*QKD+cA+4)),
                   fma4(qmB, LD4(g4, 3*QKD+cA+4),  LD4(b4, 3*QKD+cA+4)));
  float4 wC = mul4(fma4(qmC, LD4(g4, 2*QKD+cA+32), LD4(b4, 2*QKD+cA+32)),
                   fma4(qmC, LD4(g4, 3*QKD+cA+32), LD4(b4, 3*QKD+cA+32)));
  float4 wD = mul4(fma4(qmD, LD4(g4, 2*QKD+cA+36), LD4(b4, 2*QKD+cA+36)),
                   fma4(qmD, LD4(g4, 3*QKD+cA+36), LD4(b4, 3*QKD+cA+36)));
  if (sh) { wA = mul4(wA, wA); wB = mul4(wB, wB); wC = mul4(wC, wC); wD = mul4(wD, wD); }
  const float scl = 0.17677669529663687f;     // 1/sqrt(32)
  // ---- Q fragment (B-operand: col = lr = q-row i): raw qk row * W ----
  const int qsrc = sh ? (irow ? irow - 1 : 0) : irow;
  const u16* qrow = qk + (grpRow + qsrc) * QKD + cA;
  s16x8 qb0 = mul8(*(const s16x8*)qrow,        wA, wB);
  s16x8 qb1 = mul8(*(const s16x8*)(qrow + 32), wC, wD);
  // ---- QK^T (A = RAW qk row-tile, causally bounded) ----
  f32x4 sfr[16];
  #pragma unroll
  for (int nt = 0; nt < 16; ++nt) if (nt <= ntmax) {
    const int jr = nt * 16 + lr;
    const int ksrc = sh ? (jr ? jr - 1 : 0) : jr;
    const u16* kr = qk + (grpRow + ksrc) * QKD + cA;
    s16x8 ka0 = *(const s16x8*)kr;
    s16x8 ka1 = *(const s16x8*)(kr + 32);
    f32x4 c = {0.f, 0.f, 0.f, 0.f};
    c = __builtin_amdgcn_mfma_f32_16x16x32_bf16(ka0, qb0, c, 0, 0, 0);
    c = __builtin_amdgcn_mfma_f32_16x16x32_bf16(ka1, qb1, c, 0, 0, 0);
    sfr[nt] = c;
  }
  // ---- add per-j bias ----
  const float* bp = bjs + ((size_t)bg * 4 + h) * NPG;
  #pragma unroll
  for (int nt = 0; nt < 16; ++nt) if (nt <= ntmax) {
    float4 bv = LD4(bp, nt * 16 + lq * 4);
    f32x4 c = sfr[nt];
    c[0] += bv.x; c[1] += bv.y; c[2] += bv.z; c[3] += bv.w;
    sfr[nt] = c;
  }
  // ---- softmax over j for this lane's row ----
  float mx = -3.4e38f;
  #pragma unroll
  for (int nt = 0; nt < 16; ++nt) if (nt <= ntmax) {
    #pragma unroll
    for (int r = 0; r < 4; ++r) {
      int j = nt * 16 + lq * 4 + r;
      if (j <= irow) mx = fmaxf(mx, sfr[nt][r] * scl);
    }
  }
  mx = fmaxf(mx, __shfl_xor(mx, 16));
  mx = fmaxf(mx, __shfl_xor(mx, 32));
  float sum = 0.f;
  u32 p01[16], p23[16];
  #pragma unroll
  for (int nt = 0; nt < 16; ++nt) { p01[nt] = 0u; p23[nt] = 0u; }
  #pragma unroll
  for (int nt = 0; nt < 16; ++nt) if (nt <= ntmax) {
    int j = nt * 16 + lq * 4;
    float e0 = (j + 0 <= irow) ? __expf(sfr[nt][0] * scl - mx) : 0.f;
    float e1 = (j + 1 <= irow) ? __expf(sfr[nt][1] * scl - mx) : 0.f;
    float e2 = (j + 2 <= irow) ? __expf(sfr[nt][2] * scl - mx) : 0.f;
    float e3 = (j + 3 <= irow) ? __expf(sfr[nt][3] * scl - mx) : 0.f;
    sum += (e0 + e1) + (e2 + e3);
    p01[nt] = (u32)f2bf(e0) | ((u32)f2bf(e1) << 16);
    p23[nt] = (u32)f2bf(e2) | ((u32)f2bf(e3) << 16);
  }
  sum += __shfl_xor(sum, 16);
  sum += __shfl_xor(sum, 32);
  const float inv = 1.f / sum;
  // ---- build P^T B-frags via in-wave shuffles ----
  const int srcA = (l & 15) | ((l & 16) << 1);   // lr + 32*(lq&1)
  const int srcB = srcA + 16;
  const bool hi = (l >= 32);
  s16x8 bfr[8];
  #pragma unroll
  for (int jt = 0; jt < 8; ++jt) if (jt <= jtmax) {
    u32 a0 = __shfl((int)p01[2 * jt], srcA), a1 = __shfl((int)p23[2 * jt], srcA);
    u32 a2 = __shfl((int)p01[2 * jt], srcB), a3 = __shfl((int)p23[2 * jt], srcB);
    u32 b0 = __shfl((int)p01[2 * jt + 1], srcA), b1 = __shfl((int)p23[2 * jt + 1], srcA);
    u32 b2 = __shfl((int)p01[2 * jt + 1], srcB), b3 = __shfl((int)p23[2 * jt + 1], srcB);
    union { u32 u[4]; s16x8 v; } bb2;
    bb2.u[0] = hi ? b0 : a0; bb2.u[1] = hi ? b1 : a1;
    bb2.u[2] = hi ? b2 : a2; bb2.u[3] = hi ? b3 : a3;
    bfr[jt] = bb2.v;
  }
  // ---- PV over 8 e-octants: stage once per block (both tiles share the LDS tile) ----
  const u16* vtb = hidt + (size_t)bg * (512 * 256);
  const size_t srow = grpRow + irow;
  const u16* gp = gate + srow * HIDD;
  u16* op = out4 + srow * 2048 + ((size_t)h << 9);
  const int vr = t >> 3, vc = t & 7;          // 64 rows x 8 col8 per pass
  const int nj8 = (jtmaxStage + 1) * 4;       // col8 count to stage
  for (int oct = 0; oct < 8; ++oct) {
    __syncthreads();                          // previous octant fully consumed
    const u16* src = vtb + (size_t)oct * 64 * 256;
    for (int cc = vc; cc < nj8; cc += 8)
      *(uint4*)&Vs[vr][cc * 8] = *(const uint4*)(src + (size_t)vr * 256 + cc * 8);
    __syncthreads();
    f32x4 acc[4];
    #pragma unroll
    for (int ef = 0; ef < 4; ++ef) acc[ef] = (f32x4){0.f, 0.f, 0.f, 0.f};
    #pragma unroll
    for (int jt = 0; jt < 8; ++jt) if (jt <= jtmax) {
      __builtin_amdgcn_s_setprio(1);
      #pragma unroll
      for (int ef = 0; ef < 4; ++ef) {
        s16x8 va = *(const s16x8*)&Vs[ef * 16 + lr][jt * 32 + 8 * lq];
        acc[ef] = __builtin_amdgcn_mfma_f32_16x16x32_bf16(va, bfr[jt], acc[ef], 0, 0, 0);
      }
      __builtin_amdgcn_s_setprio(0);
    }
    #pragma unroll
    for (int ef = 0; ef < 4; ++ef) {
      const int e = oct * 64 + ef * 16 + lq * 4;
      ushort4 gu = *(const ushort4*)(gp + e);
      ushort4 ov;
      ov.x = f2bf(silu_fast(acc[ef][0] * inv) * bf2f(gu.x));
      ov.y = f2bf(silu_fast(acc[ef][1] * inv) * bf2f(gu.y));
      ov.z = f2bf(silu_fast(acc[ef][2] * inv) * bf2f(gu.z));
      ov.w = f2bf(silu_fast(acc[ef][3] * inv) * bf2f(gu.w));
      *(ushort4*)(op + e) = ov;
    }
  }
}

// ---------------- Kernel 5: m97-style MFMA GEMM residual(2560) @ w_out + epilogue ----------------
__global__ __launch_bounds__(256, 4) void k_gemm2m(const u16* __restrict__ hidr,
    const u16* __restrict__ out4, const u16* __restrict__ wt,
    const u16* __restrict__ xg, float* __restrict__ out) {
  __shared__ u16 As[128 * 64];
  __shared__ u16 Bs[128 * 64];
  const int t = threadIdx.x;
  const int blk = blockIdx.x;                 // 1024 = 8 XCD x 32 m x 4 n
  const int xcd = blk & 7;
  const int loc = blk >> 3;                   // 0..127
  const int m0 = (xcd * 32 + (loc >> 2)) * 128;
  const int n0 = (loc & 3) * 128;
  const int w = t >> 6, l = t & 63, lr = l & 15, lq = l >> 4;
  const int wr = (w >> 1) * 64, wc = (w & 1) * 64;
  const int rI = l >> 3;
  const int c8 = (l & 7) ^ rI;
  const int slotA = lq ^ (lr & 7);
  const int slotB = (4 + lq) ^ (lr & 7);
  f32x4 acc[4][4];
  #pragma unroll
  for (int i = 0; i < 4; ++i)
    #pragma unroll
    for (int j = 0; j < 4; ++j) acc[i][j] = (f32x4){0.f, 0.f, 0.f, 0.f};
  for (int tt = 0; tt < 40; ++tt) {
    const int k0 = tt * 64;
    const u16* ab; size_t ald; int ko;
    if (k0 < 512) { ab = hidr; ald = 512;  ko = k0; }
    else          { ab = out4; ald = 2048; ko = k0 - 512; }
    #pragma unroll
    for (int i = 0; i < 4; ++i) {
      const int br = w * 32 + i * 8;
      gl_lds16(ab + (size_t)(m0 + br + rI) * ald + ko + c8 * 8, &As[br * 64]);
      gl_lds16(wt + (size_t)(n0 + br + rI) * 2560 + k0 + c8 * 8, &Bs[br * 64]);
    }
    __syncthreads();
    #pragma unroll
    for (int kk = 0; kk < 2; ++kk) {
      const int slot = kk ? slotB : slotA;
      s16x8 af[4], bf[4];
      #pragma unroll
      for (int fi = 0; fi < 4; ++fi) af[fi] = *(const s16x8*)&As[(wr + fi * 16 + lr) * 64 + slot * 8];
      #pragma unroll
      for (int fj = 0; fj < 4; ++fj) bf[fj] = *(const s16x8*)&Bs[(wc + fj * 16 + lr) * 64 + slot * 8];
      #pragma unroll
      for (int fi = 0; fi < 4; ++fi)
        #pragma unroll
        for (int fj = 0; fj < 4; ++fj)
          acc[fi][fj] = __builtin_amdgcn_mfma_f32_16x16x32_bf16(af[fi], bf[fj], acc[fi][fj], 0, 0, 0);
    }
    __syncthreads();
  }
  #pragma unroll
  for (int fi = 0; fi < 4; ++fi)
    #pragma unroll
    for (int fj = 0; fj < 4; ++fj) {
      const int n = n0 + wc + fj * 16 + lr;
      const int mb = m0 + wr + fi * 16 + lq * 4;
      #pragma unroll
      for (int r = 0; r < 4; ++r) {
        const size_t idx = (size_t)(mb + r) * DIM + n;
        out[idx] = acc[fi][fj][r] * bf2f(xg[idx]) + out[idx];   // out holds xs (in-place)
      }
    }
}

extern "C" void kernel_launch(void* const* d_in, const int* in_sizes, int n_in,
                              void* d_out, int out_size, void* d_ws, size_t ws_size,
                              hipStream_t stream) {
  const float* x        = (const float*)d_in[0];
  const float* lg       = (const float*)d_in[1];
  const float* lb       = (const float*)d_in[2];
  const float* w_qk     = (const float*)d_in[3];
  const float* g4       = (const float*)d_in[4];
  const float* b4       = (const float*)d_in[5];
  const float* g2       = (const float*)d_in[6];
  const float* b2       = (const float*)d_in[7];
  const float* w_hidden = (const float*)d_in[8];
  const float* w_gate   = (const float*)d_in[9];
  const float* w_out    = (const float*)d_in[10];
  // ws layout (bytes), total 248,184,832 (<= R2-proven 251,723,776):
  //   QM   f32  @ 0              65,536
  //   HIDT bf16 @ 65,536     33,554,432   [bg][e][j]
  //   GATE bf16 @ 33,619,968 33,554,432   (HIDR overlays after attn)
  //   XG   bf16 @ 67,174,400 33,554,432
  //   QK   bf16 @ 100,728,832 8,388,608
  //   W1T  bf16 @ 109,117,440 1,703,936   [1664][512]
  //   WT   bf16 @ 110,821,376 2,621,440   [512][2560]
  //   OUT4 bf16 @ 113,442,816 134,217,728
  //   BJS  f32  @ 247,660,544    524,288  [bg][h][256] softmax bias
  // Overlays: HIDR (33,554,432) @ GATE  — written by k_trh AFTER attn (GATE dead).
  //           XSB  (33,554,432) @ OUT4  — written by k_ln, read by gemm1m; OUT4 is
  //                                       written by attn strictly AFTER gemm1m reads.
  // xs (f32) lives in d_out, overwritten in-place by k_gemm2m epilogue.
  if (ws_size < 248184832ull) return;
  char* ws = (char*)d_ws;
  float* QM   = (float*)(ws + 0);
  u16*   HIDT = (u16*)  (ws + 65536);
  u16*   GATE = (u16*)  (ws + 33619968);
  u16*   XG   = (u16*)  (ws + 67174400);
  u16*   QKb  = (u16*)  (ws + 100728832);
  u16*   W1T  = (u16*)  (ws + 109117440);
  u16*   WT   = (u16*)  (ws + 110821376);
  u16*   OUT4 = (u16*)  (ws + 113442816);
  u16*   XSB  = (u16*)  (ws + 113442816);   // overlay on OUT4 (pre-attn lifetime)
  u16*   HIDR = (u16*)  (ws + 33619968);    // overlay on GATE (post-attn)
  float* BJS  = (float*)(ws + 247660544);
  float* XS   = (float*)d_out;
  float* OUT  = (float*)d_out;

  k_ln<<<BB * SEQ, 256, 0, stream>>>(x, lg, lb, XS, XSB);
  k_trw<<<dim3(8, 2),  256, 0, stream>>>(w_qk,     W1T, 128,  512,  0);
  k_trw<<<dim3(8, 16), 256, 0, stream>>>(w_hidden, W1T, 1024, 512,  128);
  k_trw<<<dim3(8, 8),  256, 0, stream>>>(w_gate,   W1T, 512,  512,  1152);
  k_trw<<<dim3(40, 8), 256, 0, stream>>>(w_out,    WT,  512,  2560, 0);
  k_gemm1m<<<3328, 256, 0, stream>>>(XSB, W1T, QKb, HIDT, GATE, XG);
  k_qkmb<<<BB * GG, 256, 0, stream>>>(QKb, g4, b4, g2, b2, QM, BJS);
  k_attn<<<BB * GG * 8, 512, 0, stream>>>(QKb, QM, g4, b4, BJS, HIDT, GATE, OUT4);
  k_trh<<<dim3(4, 8, 128), 256, 0, stream>>>(HIDT, HIDR);
  k_gemm2m<<<1024, 256, 0, stream>>>(HIDR, OUT4, WT, XG, OUT);
}